// Round 4
// baseline (93.866 us; speedup 1.0000x reference)
//
#include <hip/hip_runtime.h>

// HistoLoss: B=1024, T=256, C=16, NB=64; TC=4096; x flat = [b][tc]
//
// Timeline budget (round-3 finding): harness fixed cost ~50 us of the 92.9
// (256 MB ws re-poison fill 43.5 us + input restores + graph node gaps).
// k1 inferred ~25-28 us vs 10.2 us VALU floor -> this round attacks k1 issue
// density (ds_read_b128 over a transposed x-tile) and fuses k2+k3.
//
// k1: block = 128 thr (16 c x 8 kq), one block per (t, 64-b chunk), 16 chunks
//     -> grid 4096 -> 16 blocks/CU = 8 waves/SIMD. x staged TRANSPOSED in LDS
//     as xs[c][68] so the bin loop reads 4 b's with one ds_read_b128
//     (row stride 68 words -> the 8 c-groups of a wave hit disjoint 4-bank
//     spans: conflict-free). Inner: per 4 b x 8 bins = 32 independent
//     (v_sub, v_cmp|abs|, addc) chains per b128 read. Counts <=64 -> 8 x u8
//     pack -> one 8B store. Swizzle t = bidx & 255 (all chunks of a t on one
//     XCD; each 64B x line read by exactly one block -> x fetch == 16 MiB).
// k2: 4 items/thread (u32 = 4 packed counts per chunk), loss terms,
//     block-reduce, one atomicAdd per block (k1 block 0 zeroes out[0];
//     stream-ordered). k3 eliminated (one fewer node gap).

#define T_DIM   256
#define C_DIM   16
#define NB      64
#define TC      4096
#define CHUNKS  16
#define BCH     64             // b per chunk (counts fit u8)
#define KPT     8              // k per thread
#define XPITCH  68             // xs row pitch in floats (64 + 4 pad)

__global__ __launch_bounds__(128, 8) void histo_count_kernel(
    const float* __restrict__ x,       // [1024, 4096]
    const float* __restrict__ locs,    // [4096, 64]
    const float* __restrict__ deltas,  // [4096]
    unsigned char* __restrict__ counts,// [CHUNKS][4096][64] u8
    float* __restrict__ out)           // [1] (zeroed here for k2's atomics)
{
    __shared__ float xs[C_DIM * XPITCH];   // 16 x 68 floats = 4352 B
    const int tid   = threadIdx.x;
    const int t     = blockIdx.x & 255;
    const int chunk = blockIdx.x >> 8;

    if (blockIdx.x == 0 && tid == 0) out[0] = 0.0f;

    // Stage x[chunk*64 .. +63][t*16 .. +15] -> xs[c][b] (transposed).
    // 2 float4 loads/thread (line-exact global fetch), 8 scalar LDS writes
    // (2 lanes/bank -> free).
    const float* xbase = x + (size_t)(chunk * BCH) * TC + t * C_DIM;
#pragma unroll
    for (int p = 0; p < 2; ++p) {
        const int lin = p * 512 + tid * 4;
        const int bi  = lin >> 4;
        const int c4  = lin & 15;
        const float4 v = *(const float4*)(xbase + (size_t)bi * TC + c4);
        xs[(c4 + 0) * XPITCH + bi] = v.x;
        xs[(c4 + 1) * XPITCH + bi] = v.y;
        xs[(c4 + 2) * XPITCH + bi] = v.z;
        xs[(c4 + 3) * XPITCH + bi] = v.w;
    }

    const int c  = tid >> 3;           // 0..15
    const int kq = tid & 7;            // 0..7 -> bins [kq*8, kq*8+8)
    const int tc = t * C_DIM + c;

    const float h = 0.5f * deltas[tc];
    float lc[KPT];
    const float* lp = locs + (size_t)tc * NB + kq * KPT;
#pragma unroll
    for (int j = 0; j < KPT; ++j) lc[j] = lp[j];

    int cnt[KPT];
#pragma unroll
    for (int j = 0; j < KPT; ++j) cnt[j] = 0;

    __syncthreads();

    // 16 iters x (1 ds_read_b128 + 32 independent 3-op indicator chains).
    const float4* xr = (const float4*)(xs + c * XPITCH);
#pragma unroll 4
    for (int g = 0; g < BCH / 4; ++g) {
        const float4 xv = xr[g];
#pragma unroll
        for (int j = 0; j < KPT; ++j) {
            cnt[j] += (fabsf(xv.x - lc[j]) < h) ? 1 : 0;
            cnt[j] += (fabsf(xv.y - lc[j]) < h) ? 1 : 0;
            cnt[j] += (fabsf(xv.z - lc[j]) < h) ? 1 : 0;
            cnt[j] += (fabsf(xv.w - lc[j]) < h) ? 1 : 0;
        }
    }

    unsigned long long pack = 0;
#pragma unroll
    for (int j = 0; j < KPT; ++j)
        pack |= (unsigned long long)(unsigned)cnt[j] << (8 * j);
    *(unsigned long long*)(counts + (size_t)chunk * (TC * NB)
                                  + (size_t)tc * NB + kq * KPT) = pack;
}

__global__ __launch_bounds__(256) void histo_loss_kernel(
    const unsigned char* __restrict__ counts, // [CHUNKS][4096][64]
    const float* __restrict__ deltas,         // [4096]
    const float* __restrict__ dens,           // [4096, 64]
    float* __restrict__ out)                  // [1]
{
    const int gid = blockIdx.x * 256 + threadIdx.x;
    const int i0  = gid * 4;                  // 4 consecutive items, same tc

    int cnt[4] = {0, 0, 0, 0};
#pragma unroll
    for (int ch = 0; ch < CHUNKS; ++ch) {
        const unsigned u = *(const unsigned*)(counts + (size_t)ch * (TC * NB) + i0);
#pragma unroll
        for (int q = 0; q < 4; ++q)
            cnt[q] += (int)((u >> (8 * q)) & 0xffu);
    }

    const float delta = deltas[i0 >> 6];
    const float4 dv = *(const float4*)(dens + i0);
    // Reference order: (cnt/1024) exact, then / delta.
    float s = fabsf((cnt[0] * (1.0f / 1024.0f)) / delta - dv.x)
            + fabsf((cnt[1] * (1.0f / 1024.0f)) / delta - dv.y)
            + fabsf((cnt[2] * (1.0f / 1024.0f)) / delta - dv.z)
            + fabsf((cnt[3] * (1.0f / 1024.0f)) / delta - dv.w);

#pragma unroll
    for (int off = 32; off > 0; off >>= 1)
        s += __shfl_down(s, off, 64);

    __shared__ float sb[4];
    if ((threadIdx.x & 63) == 0) sb[threadIdx.x >> 6] = s;
    __syncthreads();

    if (threadIdx.x == 0)   // REG * mean over (t,c,k) = sum / 262144
        atomicAdd(out, (sb[0] + sb[1] + sb[2] + sb[3]) * (1.0f / 262144.0f));
}

extern "C" void kernel_launch(void* const* d_in, const int* in_sizes, int n_in,
                              void* d_out, int out_size, void* d_ws, size_t ws_size,
                              hipStream_t stream) {
    const float* x      = (const float*)d_in[0];  // x_fake    [1024,256,16]
    const float* locs   = (const float*)d_in[1];  // locs      [256,16,64]
    const float* deltas = (const float*)d_in[2];  // deltas    [256,16]
    const float* dens   = (const float*)d_in[3];  // densities [256,16,64]
    float* out = (float*)d_out;
    unsigned char* cnts = (unsigned char*)d_ws;   // 4 MB scratch

    histo_count_kernel<<<T_DIM * CHUNKS, 128, 0, stream>>>(x, locs, deltas, cnts, out);
    histo_loss_kernel<<<(TC * NB) / (256 * 4), 256, 0, stream>>>(cnts, deltas, dens, out);
}